// Round 1
// baseline (238.563 us; speedup 1.0000x reference)
//
#include <hip/hip_runtime.h>
#include <hip/hip_bf16.h>
#include <stdint.h>

// ---------------------------------------------------------------------------
// DAReLoss: SupCon(reparam features) + JSD(normalized Gaussian stats)
// B=4096, D=512, N=2B=8192, TAU=1, LAM=1
// ---------------------------------------------------------------------------

typedef __attribute__((ext_vector_type(4))) float f32x4;
typedef __attribute__((ext_vector_type(8))) short bf16x8;

#define BDIM 4096
#define DDIM 512
#define NROWS 8192
#define NCS 32           // column splits for the sim/LSE kernel
#define LDAP 40          // padded LDS stride (32 + 8 bf16)

// ----------------------------- threefry-2x32 -------------------------------
__device__ __forceinline__ void tf_round(uint32_t& x0, uint32_t& x1, int r){
  x0 += x1;
  x1 = (x1 << r) | (x1 >> (32 - r));
  x1 ^= x0;
}

__device__ __forceinline__ void threefry2x32(uint32_t k0, uint32_t k1,
                                             uint32_t c0, uint32_t c1,
                                             uint32_t& o0, uint32_t& o1){
  uint32_t ks2 = k0 ^ k1 ^ 0x1BD11BDAu;
  uint32_t x0 = c0 + k0, x1 = c1 + k1;
  tf_round(x0,x1,13); tf_round(x0,x1,15); tf_round(x0,x1,26); tf_round(x0,x1,6);
  x0 += k1; x1 += ks2 + 1u;
  tf_round(x0,x1,17); tf_round(x0,x1,29); tf_round(x0,x1,16); tf_round(x0,x1,24);
  x0 += ks2; x1 += k0 + 2u;
  tf_round(x0,x1,13); tf_round(x0,x1,15); tf_round(x0,x1,26); tf_round(x0,x1,6);
  x0 += k0; x1 += k1 + 3u;
  tf_round(x0,x1,17); tf_round(x0,x1,29); tf_round(x0,x1,16); tf_round(x0,x1,24);
  x0 += k1; x1 += ks2 + 4u;
  tf_round(x0,x1,13); tf_round(x0,x1,15); tf_round(x0,x1,26); tf_round(x0,x1,6);
  x0 += ks2; x1 += k0 + 5u;
  o0 = x0; o1 = x1;
}

// erfinv, Giles single-precision polynomial (same family XLA uses)
__device__ __forceinline__ float erfinv_f32(float x){
  float w = -log1pf(-x*x);
  float p;
  if (w < 5.0f){
    w -= 2.5f;
    p = 2.81022636e-08f;
    p = fmaf(p,w, 3.43273939e-07f);
    p = fmaf(p,w,-3.5233877e-06f);
    p = fmaf(p,w,-4.39150654e-06f);
    p = fmaf(p,w, 0.00021858087f);
    p = fmaf(p,w,-0.00125372503f);
    p = fmaf(p,w,-0.00417768164f);
    p = fmaf(p,w, 0.246640727f);
    p = fmaf(p,w, 1.50140941f);
  } else {
    w = sqrtf(w) - 3.0f;
    p = -0.000200214257f;
    p = fmaf(p,w, 0.000100950558f);
    p = fmaf(p,w, 0.00134934322f);
    p = fmaf(p,w,-0.00367342844f);
    p = fmaf(p,w, 0.00573950773f);
    p = fmaf(p,w,-0.0076224613f);
    p = fmaf(p,w, 0.00943887047f);
    p = fmaf(p,w, 1.00167406f);
    p = fmaf(p,w, 2.83297682f);
  }
  return p*x;
}

// jax.random.normal element idx of a (4096,512) draw, legacy threefry layout:
// bits = threefry(key, iota(2^21)) with x0=[0,2^20), x1=[2^20,2^21)
__device__ __forceinline__ float jax_normal_elem(uint32_t k0, uint32_t k1, uint32_t idx){
  uint32_t p = idx & 0xFFFFFu;
  uint32_t hi = idx >> 20;
  uint32_t o0, o1;
  threefry2x32(k0, k1, p, p + 0x100000u, o0, o1);
  uint32_t bits = hi ? o1 : o0;
  float f = __uint_as_float((bits >> 9) | 0x3F800000u) - 1.0f;   // [0,1)
  const float lo = -0.99999994f;                                  // nextafter(-1,0)
  float v = fmaf(f, 2.0f, lo);                                    // (hi-lo) rounds to 2.0f
  v = fmaxf(lo, v);
  return 1.41421354f * erfinv_f32(v);                             // sqrt(2) in f32
}

__device__ __forceinline__ unsigned short f2bf(float f){
  uint32_t u = __float_as_uint(f);
  u += 0x7FFFu + ((u >> 16) & 1u);   // RNE
  return (unsigned short)(u >> 16);
}

// ------------------------- K1: features + normalize ------------------------
// One block per feature row (8192). Computes eps, x, row L2 norm, stores bf16 Xn.
__global__ __launch_bounds__(256) void k_feats(const float* __restrict__ mu,
                                               const float* __restrict__ mu_cap,
                                               const float* __restrict__ lv,
                                               const float* __restrict__ lv_cap,
                                               unsigned short* __restrict__ Xn){
  int r    = blockIdx.x;          // 0..8191
  int view = r >> 12;             // 0: x (mu,lv,eps1) | 1: x_cap
  int row  = r & 4095;
  const float* M = view ? mu_cap : mu;
  const float* L = view ? lv_cap : lv;

  // split(key(42)): ek1=(a0,a1), ek2=(b0,b1)
  uint32_t a0,a1,b0,b1;
  threefry2x32(0u, 42u, 0u, 2u, a0, b0);
  threefry2x32(0u, 42u, 1u, 3u, a1, b1);
  uint32_t k0 = view ? b0 : a0;
  uint32_t k1 = view ? b1 : a1;

  int t = threadIdx.x;
  float xv[2];
  float ss = 0.f;
  #pragma unroll
  for (int q = 0; q < 2; ++q){
    int c = t + q*256;
    uint32_t idx = (uint32_t)row*512u + (uint32_t)c;
    float e  = jax_normal_elem(k0, k1, idx);
    size_t g = (size_t)row*512 + c;
    float v  = M[g] + expf(0.5f*L[g]) * e;
    xv[q] = v;
    ss += v*v;
  }
  __shared__ float sred[4];
  #pragma unroll
  for (int o = 32; o; o >>= 1) ss += __shfl_down(ss, o);
  if ((t & 63) == 0) sred[t >> 6] = ss;
  __syncthreads();
  float tot = sred[0] + sred[1] + sred[2] + sred[3];
  float inv = 1.0f / fmaxf(sqrtf(tot), 1e-12f);
  #pragma unroll
  for (int q = 0; q < 2; ++q){
    int c = t + q*256;
    Xn[(size_t)r*512 + c] = f2bf(xv[q]*inv);
  }
}

// -------------------- K2: sim = Xn Xn^T, streaming LSE ---------------------
// Grid: 64 row-blocks x 32 col-splits. Each block: 128 rows x 256 cols,
// K=512 in 16 steps of BK=32. 4 waves (2x2), each 64x64 via 4x4 MFMA frags.
__global__ __launch_bounds__(256) void k_simlse(const unsigned short* __restrict__ Xn,
                                                float* __restrict__ rowsumP, // [NCS][8192]
                                                float* __restrict__ possim){ // [8192]
  int rb = blockIdx.x >> 5;
  int cs = blockIdx.x & 31;
  int rowbase = rb * 128;

  int tid = threadIdx.x;
  int wid = tid >> 6, l = tid & 63;
  int wr = wid >> 1, wc = wid & 1;
  int l15 = l & 15, l4 = l >> 4;

  __shared__ unsigned short As[128 * LDAP];
  __shared__ unsigned short Bs[128 * LDAP];
  __shared__ float rs_lds[2][128];

  float rsum[4][4];
  #pragma unroll
  for (int mi = 0; mi < 4; ++mi)
    #pragma unroll
    for (int r = 0; r < 4; ++r) rsum[mi][r] = 0.f;

  int tr = tid >> 2, tc = tid & 3;

  for (int jj = 0; jj < 2; ++jj){
    int colbase = (cs*2 + jj) * 128;

    f32x4 acc[4][4];
    #pragma unroll
    for (int mi = 0; mi < 4; ++mi)
      #pragma unroll
      for (int ni = 0; ni < 4; ++ni) acc[mi][ni] = f32x4{0.f,0.f,0.f,0.f};

    for (int k = 0; k < 16; ++k){
      // stage A[128][32], B[128][32] via regs (padding-friendly)
      #pragma unroll
      for (int p = 0; p < 2; ++p){
        int row = p*64 + tr;
        uint4 va = *(const uint4*)(Xn + ((size_t)(rowbase + row)*512 + k*32 + tc*8));
        uint4 vb = *(const uint4*)(Xn + ((size_t)(colbase + row)*512 + k*32 + tc*8));
        *(uint4*)&As[row*LDAP + tc*8] = va;
        *(uint4*)&Bs[row*LDAP + tc*8] = vb;
      }
      __syncthreads();

      bf16x8 af[4], bfr[4];
      #pragma unroll
      for (int mi = 0; mi < 4; ++mi)
        af[mi] = *(const bf16x8*)&As[(wr*64 + mi*16 + l15)*LDAP + l4*8];
      #pragma unroll
      for (int ni = 0; ni < 4; ++ni)
        bfr[ni] = *(const bf16x8*)&Bs[(wc*64 + ni*16 + l15)*LDAP + l4*8];

      #pragma unroll
      for (int mi = 0; mi < 4; ++mi)
        #pragma unroll
        for (int ni = 0; ni < 4; ++ni)
          acc[mi][ni] = __builtin_amdgcn_mfma_f32_16x16x32_bf16(af[mi], bfr[ni], acc[mi][ni], 0, 0, 0);
      __syncthreads();
    }

    // consume tile: exp + rowsum, diagonal mask, positive-pair grab
    #pragma unroll
    for (int mi = 0; mi < 4; ++mi){
      int grow_b = rowbase + wr*64 + mi*16 + l4*4;
      #pragma unroll
      for (int ni = 0; ni < 4; ++ni){
        int gcol = colbase + wc*64 + ni*16 + l15;
        #pragma unroll
        for (int r = 0; r < 4; ++r){
          int grow = grow_b + r;
          float v = acc[mi][ni][r];
          if (gcol == ((grow + 4096) & 8191)) possim[grow] = v;
          if (gcol != grow) rsum[mi][r] += __expf(v);
        }
      }
    }
  }

  // reduce rsum across the 16 column-lanes, combine wc halves, write partial
  #pragma unroll
  for (int mi = 0; mi < 4; ++mi){
    #pragma unroll
    for (int r = 0; r < 4; ++r){
      float v = rsum[mi][r];
      #pragma unroll
      for (int o = 1; o < 16; o <<= 1) v += __shfl_xor(v, o);
      if (l15 == 0) rs_lds[wc][wr*64 + mi*16 + l4*4 + r] = v;
    }
  }
  __syncthreads();
  if (tid < 128){
    rowsumP[(size_t)cs*8192 + rowbase + tid] = rs_lds[0][tid] + rs_lds[1][tid];
  }
}

// ------------------------------ K3: JSD ------------------------------------
__global__ __launch_bounds__(256) void k_jsd(const float* __restrict__ mu,
                                             const float* __restrict__ mu_cap,
                                             const float* __restrict__ lv,
                                             const float* __restrict__ lv_cap,
                                             float* __restrict__ jsd_row){
  int r = blockIdx.x;
  int t = threadIdx.x;
  size_t base = (size_t)r * 512;

  float m[2], mc[2], a[2], b[2];
  float sm = 0.f, smc = 0.f, sa = 0.f, sb = 0.f;
  #pragma unroll
  for (int q = 0; q < 2; ++q){
    int c = t + q*256;
    m[q]  = mu[base + c];     sm  += m[q]*m[q];
    mc[q] = mu_cap[base + c]; smc += mc[q]*mc[q];
    a[q]  = lv[base + c];     sa  += a[q]*a[q];
    b[q]  = lv_cap[base + c]; sb  += b[q]*b[q];
  }
  __shared__ float sred[4][4];
  #pragma unroll
  for (int o = 32; o; o >>= 1){
    sm  += __shfl_down(sm,  o);
    smc += __shfl_down(smc, o);
    sa  += __shfl_down(sa,  o);
    sb  += __shfl_down(sb,  o);
  }
  if ((t & 63) == 0){
    int w = t >> 6;
    sred[w][0] = sm; sred[w][1] = smc; sred[w][2] = sa; sred[w][3] = sb;
  }
  __syncthreads();
  float tm  = sred[0][0]+sred[1][0]+sred[2][0]+sred[3][0];
  float tmc = sred[0][1]+sred[1][1]+sred[2][1]+sred[3][1];
  float ta  = sred[0][2]+sred[1][2]+sred[2][2]+sred[3][2];
  float tb  = sred[0][3]+sred[1][3]+sred[2][3]+sred[3][3];
  float im  = 1.f / fmaxf(sqrtf(tm),  1e-12f);
  float imc = 1.f / fmaxf(sqrtf(tmc), 1e-12f);
  float ia  = 1.f / fmaxf(sqrtf(ta),  1e-12f);
  float ib  = 1.f / fmaxf(sqrtf(tb),  1e-12f);

  float accv = 0.f;
  #pragma unroll
  for (int q = 0; q < 2; ++q){
    float an = m[q]*im, bn = mc[q]*imc;
    float al = a[q]*ia, bl = b[q]*ib;
    float ea = expf(al), eb = expf(bl);
    float varm = 0.5f*(ea + eb);
    float lvm  = logf(varm + 1e-8f);
    float v2   = expf(lvm);
    float den  = v2 + 1e-8f;
    float dm   = 0.5f*(an - bn);
    float dm2  = dm*dm;
    float t1 = (ea + 1e-8f)/den + (lvm - al) + dm2/den - 1.f;
    float t2 = (eb + 1e-8f)/den + (lvm - bl) + dm2/den - 1.f;
    accv += t1 + t2;
  }
  __shared__ float sred2[4];
  #pragma unroll
  for (int o = 32; o; o >>= 1) accv += __shfl_down(accv, o);
  if ((t & 63) == 0) sred2[t >> 6] = accv;
  __syncthreads();
  if (t == 0)
    jsd_row[r] = 0.25f * (sred2[0]+sred2[1]+sred2[2]+sred2[3]);
}

// ------------------- K4a: per-256-row (lse - pos) partials ------------------
__global__ __launch_bounds__(256) void k_lsepart(const float* __restrict__ rowsumP,
                                                 const float* __restrict__ possim,
                                                 float* __restrict__ part){
  int i = blockIdx.x*256 + threadIdx.x;
  float s = 0.f;
  #pragma unroll 8
  for (int cs = 0; cs < NCS; ++cs) s += rowsumP[(size_t)cs*8192 + i];
  float v = logf(s) - possim[i];

  __shared__ float sred[4];
  int t = threadIdx.x;
  #pragma unroll
  for (int o = 32; o; o >>= 1) v += __shfl_down(v, o);
  if ((t & 63) == 0) sred[t >> 6] = v;
  __syncthreads();
  if (t == 0) part[blockIdx.x] = sred[0]+sred[1]+sred[2]+sred[3];
}

// --------------------------- K4b: final combine -----------------------------
__global__ __launch_bounds__(256) void k_final(const float* __restrict__ part,
                                               const float* __restrict__ jsd_row,
                                               float* __restrict__ out){
  int t = threadIdx.x;
  float s = (t < 32) ? part[t] : 0.f;
  float j = 0.f;
  #pragma unroll
  for (int q = 0; q < 16; ++q) j += jsd_row[t + q*256];

  __shared__ float sr[4], jr[4];
  float ss = s, jj = j;
  #pragma unroll
  for (int o = 32; o; o >>= 1){ ss += __shfl_down(ss, o); jj += __shfl_down(jj, o); }
  if ((t & 63) == 0){ sr[t >> 6] = ss; jr[t >> 6] = jj; }
  __syncthreads();
  if (t == 0){
    float base = (sr[0]+sr[1]+sr[2]+sr[3]) / (8192.f * (1.f + 1e-5f));
    float jsd  = (jr[0]+jr[1]+jr[2]+jr[3]) / 4096.f;
    out[0] = base + jsd;   // LAM = 1
  }
}

// ---------------------------------------------------------------------------
extern "C" void kernel_launch(void* const* d_in, const int* in_sizes, int n_in,
                              void* d_out, int out_size, void* d_ws, size_t ws_size,
                              hipStream_t stream) {
  const float* mu     = (const float*)d_in[0];
  const float* mu_cap = (const float*)d_in[1];
  const float* lv     = (const float*)d_in[2];
  const float* lv_cap = (const float*)d_in[3];
  float* out = (float*)d_out;

  char* w = (char*)d_ws;
  unsigned short* Xn = (unsigned short*)w;                    // 8192*512*2 = 8 MB
  float* rowsumP = (float*)(w + 8388608);                     // NCS*8192*4 = 1 MB
  float* possim  = (float*)(w + 8388608 + 1048576);           // 32 KB
  float* jsd_row = (float*)(w + 8388608 + 1048576 + 32768);   // 16 KB
  float* part    = (float*)(w + 8388608 + 1048576 + 32768 + 16384); // 128 B

  k_feats <<<NROWS, 256, 0, stream>>>(mu, mu_cap, lv, lv_cap, Xn);
  k_simlse<<<64*NCS, 256, 0, stream>>>(Xn, rowsumP, possim);
  k_jsd   <<<BDIM, 256, 0, stream>>>(mu, mu_cap, lv, lv_cap, jsd_row);
  k_lsepart<<<32, 256, 0, stream>>>(rowsumP, possim, part);
  k_final <<<1, 256, 0, stream>>>(part, jsd_row, out);
}

// Round 2
// 126.483 us; speedup vs baseline: 1.8861x; 1.8861x over previous
//
#include <hip/hip_runtime.h>
#include <hip/hip_bf16.h>
#include <stdint.h>

// ---------------------------------------------------------------------------
// DAReLoss: SupCon(reparam features) + JSD(normalized Gaussian stats)
// B=4096, D=512, N=2B=8192, TAU=1, LAM=1
// Round 2: symmetric (upper-triangle) sim/LSE GEMM, m97 structure:
//   128x128 tile, BK=64, global_load_lds width=16, 2-barrier K-loop.
// ---------------------------------------------------------------------------

typedef __attribute__((ext_vector_type(4))) float f32x4;
typedef __attribute__((ext_vector_type(8))) short bf16x8;

#define BDIM 4096
#define DDIM 512
#define NROWS 8192
#define NSLOT 64         // partial-sum slots (one per 128-row block)

// ----------------------------- threefry-2x32 -------------------------------
__device__ __forceinline__ void tf_round(uint32_t& x0, uint32_t& x1, int r){
  x0 += x1;
  x1 = (x1 << r) | (x1 >> (32 - r));
  x1 ^= x0;
}

__device__ __forceinline__ void threefry2x32(uint32_t k0, uint32_t k1,
                                             uint32_t c0, uint32_t c1,
                                             uint32_t& o0, uint32_t& o1){
  uint32_t ks2 = k0 ^ k1 ^ 0x1BD11BDAu;
  uint32_t x0 = c0 + k0, x1 = c1 + k1;
  tf_round(x0,x1,13); tf_round(x0,x1,15); tf_round(x0,x1,26); tf_round(x0,x1,6);
  x0 += k1; x1 += ks2 + 1u;
  tf_round(x0,x1,17); tf_round(x0,x1,29); tf_round(x0,x1,16); tf_round(x0,x1,24);
  x0 += ks2; x1 += k0 + 2u;
  tf_round(x0,x1,13); tf_round(x0,x1,15); tf_round(x0,x1,26); tf_round(x0,x1,6);
  x0 += k0; x1 += k1 + 3u;
  tf_round(x0,x1,17); tf_round(x0,x1,29); tf_round(x0,x1,16); tf_round(x0,x1,24);
  x0 += k1; x1 += ks2 + 4u;
  tf_round(x0,x1,13); tf_round(x0,x1,15); tf_round(x0,x1,26); tf_round(x0,x1,6);
  x0 += ks2; x1 += k0 + 5u;
  o0 = x0; o1 = x1;
}

// erfinv, Giles single-precision polynomial (same family XLA uses)
__device__ __forceinline__ float erfinv_f32(float x){
  float w = -log1pf(-x*x);
  float p;
  if (w < 5.0f){
    w -= 2.5f;
    p = 2.81022636e-08f;
    p = fmaf(p,w, 3.43273939e-07f);
    p = fmaf(p,w,-3.5233877e-06f);
    p = fmaf(p,w,-4.39150654e-06f);
    p = fmaf(p,w, 0.00021858087f);
    p = fmaf(p,w,-0.00125372503f);
    p = fmaf(p,w,-0.00417768164f);
    p = fmaf(p,w, 0.246640727f);
    p = fmaf(p,w, 1.50140941f);
  } else {
    w = sqrtf(w) - 3.0f;
    p = -0.000200214257f;
    p = fmaf(p,w, 0.000100950558f);
    p = fmaf(p,w, 0.00134934322f);
    p = fmaf(p,w,-0.00367342844f);
    p = fmaf(p,w, 0.00573950773f);
    p = fmaf(p,w,-0.0076224613f);
    p = fmaf(p,w, 0.00943887047f);
    p = fmaf(p,w, 1.00167406f);
    p = fmaf(p,w, 2.83297682f);
  }
  return p*x;
}

__device__ __forceinline__ float jax_normal_elem(uint32_t k0, uint32_t k1, uint32_t idx){
  uint32_t p = idx & 0xFFFFFu;
  uint32_t hi = idx >> 20;
  uint32_t o0, o1;
  threefry2x32(k0, k1, p, p + 0x100000u, o0, o1);
  uint32_t bits = hi ? o1 : o0;
  float f = __uint_as_float((bits >> 9) | 0x3F800000u) - 1.0f;   // [0,1)
  const float lo = -0.99999994f;                                  // nextafter(-1,0)
  float v = fmaf(f, 2.0f, lo);
  v = fmaxf(lo, v);
  return 1.41421354f * erfinv_f32(v);
}

__device__ __forceinline__ unsigned short f2bf(float f){
  uint32_t u = __float_as_uint(f);
  u += 0x7FFFu + ((u >> 16) & 1u);   // RNE
  return (unsigned short)(u >> 16);
}

// ------------------------- K1: features + normalize ------------------------
__global__ __launch_bounds__(256) void k_feats(const float* __restrict__ mu,
                                               const float* __restrict__ mu_cap,
                                               const float* __restrict__ lv,
                                               const float* __restrict__ lv_cap,
                                               unsigned short* __restrict__ Xn){
  int r    = blockIdx.x;          // 0..8191
  int view = r >> 12;
  int row  = r & 4095;
  const float* M = view ? mu_cap : mu;
  const float* L = view ? lv_cap : lv;

  uint32_t a0,a1,b0,b1;
  threefry2x32(0u, 42u, 0u, 2u, a0, b0);
  threefry2x32(0u, 42u, 1u, 3u, a1, b1);
  uint32_t k0 = view ? b0 : a0;
  uint32_t k1 = view ? b1 : a1;

  int t = threadIdx.x;
  float xv[2];
  float ss = 0.f;
  #pragma unroll
  for (int q = 0; q < 2; ++q){
    int c = t + q*256;
    uint32_t idx = (uint32_t)row*512u + (uint32_t)c;
    float e  = jax_normal_elem(k0, k1, idx);
    size_t g = (size_t)row*512 + c;
    float v  = M[g] + expf(0.5f*L[g]) * e;
    xv[q] = v;
    ss += v*v;
  }
  __shared__ float sred[4];
  #pragma unroll
  for (int o = 32; o; o >>= 1) ss += __shfl_down(ss, o);
  if ((t & 63) == 0) sred[t >> 6] = ss;
  __syncthreads();
  float tot = sred[0] + sred[1] + sred[2] + sred[3];
  float inv = 1.0f / fmaxf(sqrtf(tot), 1e-12f);
  #pragma unroll
  for (int q = 0; q < 2; ++q){
    int c = t + q*256;
    Xn[(size_t)r*512 + c] = f2bf(xv[q]*inv);
  }
}

// -------------------- K2: sim = Xn Xn^T (triangular), LSE ------------------
// 2080 blocks = upper-triangle 128x128 tiles. m97 structure: BK=64,
// global_load_lds(16B), linear LDS, 4 waves (2x2), 4x4 16x16x32 frags.
// Off-diagonal tiles credit exp-sums to BOTH row-block (slot=cb) and
// col-block (slot=rb); single writer per (slot,row) -> deterministic.
__device__ __forceinline__ void gload_lds16(const unsigned short* g, unsigned short* l){
  __builtin_amdgcn_global_load_lds(
      (const __attribute__((address_space(1))) void*)g,
      (__attribute__((address_space(3))) void*)l, 16, 0, 0);
}

__global__ __launch_bounds__(256) void k_simlse(const unsigned short* __restrict__ Xn,
                                                float* __restrict__ rowsumP, // [NSLOT][8192]
                                                float* __restrict__ possim){ // [8192]
  // triangular decode: blockIdx -> (rb, cb), rb <= cb
  int t = blockIdx.x, rb = 0, cnt = 64;
  while (t >= cnt){ t -= cnt; --cnt; ++rb; }
  int cb = rb + t;
  int rowbase = rb*128, colbase = cb*128;
  bool diag    = (rb == cb);
  bool postile = (cb == rb + 32);

  __shared__ unsigned short As[128*64];
  __shared__ unsigned short Bs[128*64];
  __shared__ float red_lds[2][128];

  int tid = threadIdx.x;
  int wid = tid >> 6, l = tid & 63;
  int wr = wid >> 1, wc = wid & 1;
  int l15 = l & 15, l4 = l >> 4;

  f32x4 acc[4][4];
  #pragma unroll
  for (int mi = 0; mi < 4; ++mi)
    #pragma unroll
    for (int ni = 0; ni < 4; ++ni) acc[mi][ni] = f32x4{0.f,0.f,0.f,0.f};

  int lrow8 = l >> 3;        // 0..7: row within 8-row chunk
  int lcol8 = (l & 7) * 8;   // bf16 col offset within BK

  for (int k = 0; k < 8; ++k){
    // stage A[128][64], B[128][64] via global_load_lds (linear dest:
    // chunk base is wave-uniform, HW adds lane*16B)
    #pragma unroll
    for (int q = 0; q < 4; ++q){
      int ch = wid*4 + q;   // 0..15, 8 rows each
      const unsigned short* ga = Xn + (size_t)(rowbase + ch*8 + lrow8)*512 + k*64 + lcol8;
      const unsigned short* gb = Xn + (size_t)(colbase + ch*8 + lrow8)*512 + k*64 + lcol8;
      gload_lds16(ga, As + ch*512);
      gload_lds16(gb, Bs + ch*512);
    }
    __syncthreads();   // compiler drains vmcnt before s_barrier

    #pragma unroll
    for (int kk = 0; kk < 2; ++kk){
      bf16x8 af[4], bfr[4];
      #pragma unroll
      for (int mi = 0; mi < 4; ++mi)
        af[mi] = *(const bf16x8*)&As[(wr*64 + mi*16 + l15)*64 + kk*32 + l4*8];
      #pragma unroll
      for (int ni = 0; ni < 4; ++ni)
        bfr[ni] = *(const bf16x8*)&Bs[(wc*64 + ni*16 + l15)*64 + kk*32 + l4*8];
      #pragma unroll
      for (int mi = 0; mi < 4; ++mi)
        #pragma unroll
        for (int ni = 0; ni < 4; ++ni)
          acc[mi][ni] = __builtin_amdgcn_mfma_f32_16x16x32_bf16(af[mi], bfr[ni], acc[mi][ni], 0, 0, 0);
    }
    __syncthreads();
  }

  // ---- epilogue: exp + row/col partial sums, diag mask, pos-pair grab ----
  float rsum[4][4];
  float csum[4] = {0.f,0.f,0.f,0.f};
  #pragma unroll
  for (int mi = 0; mi < 4; ++mi)
    #pragma unroll
    for (int r = 0; r < 4; ++r) rsum[mi][r] = 0.f;

  #pragma unroll
  for (int mi = 0; mi < 4; ++mi){
    #pragma unroll
    for (int ni = 0; ni < 4; ++ni){
      int col_l = wc*64 + ni*16 + l15;
      #pragma unroll
      for (int r = 0; r < 4; ++r){
        int row_l = wr*64 + mi*16 + l4*4 + r;
        float v = acc[mi][ni][r];
        float e = __expf(v);
        if (diag){
          if (row_l != col_l) rsum[mi][r] += e;
        } else {
          rsum[mi][r] += e;
          csum[ni]    += e;
          if (postile && row_l == col_l){
            possim[rowbase + row_l] = v;           // row i, pos col i+4096
            possim[colbase + col_l] = v;           // row i+4096, pos col i (symmetric)
          }
        }
      }
    }
  }

  // row-sums: reduce across 16 col-lanes, combine wc halves, slot = cb
  #pragma unroll
  for (int mi = 0; mi < 4; ++mi){
    #pragma unroll
    for (int r = 0; r < 4; ++r){
      float v = rsum[mi][r];
      v += __shfl_xor(v, 1); v += __shfl_xor(v, 2);
      v += __shfl_xor(v, 4); v += __shfl_xor(v, 8);
      if (l15 == 0) red_lds[wc][wr*64 + mi*16 + l4*4 + r] = v;
    }
  }
  __syncthreads();
  if (tid < 128)
    rowsumP[(size_t)cb*8192 + rowbase + tid] = red_lds[0][tid] + red_lds[1][tid];

  // col-sums (transposed contribution): reduce across l4 groups, slot = rb
  if (!diag){
    __syncthreads();
    #pragma unroll
    for (int ni = 0; ni < 4; ++ni){
      float v = csum[ni];
      v += __shfl_xor(v, 16); v += __shfl_xor(v, 32);
      if (l4 == 0) red_lds[wr][wc*64 + ni*16 + l15] = v;
    }
    __syncthreads();
    if (tid < 128)
      rowsumP[(size_t)rb*8192 + colbase + tid] = red_lds[0][tid] + red_lds[1][tid];
  }
}

// ------------------------------ K3: JSD ------------------------------------
__global__ __launch_bounds__(256) void k_jsd(const float* __restrict__ mu,
                                             const float* __restrict__ mu_cap,
                                             const float* __restrict__ lv,
                                             const float* __restrict__ lv_cap,
                                             float* __restrict__ jsd_row){
  int r = blockIdx.x;
  int t = threadIdx.x;
  size_t base = (size_t)r * 512;

  float m[2], mc[2], a[2], b[2];
  float sm = 0.f, smc = 0.f, sa = 0.f, sb = 0.f;
  #pragma unroll
  for (int q = 0; q < 2; ++q){
    int c = t + q*256;
    m[q]  = mu[base + c];     sm  += m[q]*m[q];
    mc[q] = mu_cap[base + c]; smc += mc[q]*mc[q];
    a[q]  = lv[base + c];     sa  += a[q]*a[q];
    b[q]  = lv_cap[base + c]; sb  += b[q]*b[q];
  }
  __shared__ float sred[4][4];
  #pragma unroll
  for (int o = 32; o; o >>= 1){
    sm  += __shfl_down(sm,  o);
    smc += __shfl_down(smc, o);
    sa  += __shfl_down(sa,  o);
    sb  += __shfl_down(sb,  o);
  }
  if ((t & 63) == 0){
    int w = t >> 6;
    sred[w][0] = sm; sred[w][1] = smc; sred[w][2] = sa; sred[w][3] = sb;
  }
  __syncthreads();
  float tm  = sred[0][0]+sred[1][0]+sred[2][0]+sred[3][0];
  float tmc = sred[0][1]+sred[1][1]+sred[2][1]+sred[3][1];
  float ta  = sred[0][2]+sred[1][2]+sred[2][2]+sred[3][2];
  float tb  = sred[0][3]+sred[1][3]+sred[2][3]+sred[3][3];
  float im  = 1.f / fmaxf(sqrtf(tm),  1e-12f);
  float imc = 1.f / fmaxf(sqrtf(tmc), 1e-12f);
  float ia  = 1.f / fmaxf(sqrtf(ta),  1e-12f);
  float ib  = 1.f / fmaxf(sqrtf(tb),  1e-12f);

  float accv = 0.f;
  #pragma unroll
  for (int q = 0; q < 2; ++q){
    float an = m[q]*im, bn = mc[q]*imc;
    float al = a[q]*ia, bl = b[q]*ib;
    float ea = expf(al), eb = expf(bl);
    float varm = 0.5f*(ea + eb);
    float lvm  = logf(varm + 1e-8f);
    float v2   = expf(lvm);
    float den  = v2 + 1e-8f;
    float dm   = 0.5f*(an - bn);
    float dm2  = dm*dm;
    float t1 = (ea + 1e-8f)/den + (lvm - al) + dm2/den - 1.f;
    float t2 = (eb + 1e-8f)/den + (lvm - bl) + dm2/den - 1.f;
    accv += t1 + t2;
  }
  __shared__ float sred2[4];
  #pragma unroll
  for (int o = 32; o; o >>= 1) accv += __shfl_down(accv, o);
  if ((t & 63) == 0) sred2[t >> 6] = accv;
  __syncthreads();
  if (t == 0)
    jsd_row[r] = 0.25f * (sred2[0]+sred2[1]+sred2[2]+sred2[3]);
}

// ------------------- K4a: per-256-row (lse - pos) partials ------------------
__global__ __launch_bounds__(256) void k_lsepart(const float* __restrict__ rowsumP,
                                                 const float* __restrict__ possim,
                                                 float* __restrict__ part){
  int i = blockIdx.x*256 + threadIdx.x;
  float s = 0.f;
  #pragma unroll 8
  for (int cs = 0; cs < NSLOT; ++cs) s += rowsumP[(size_t)cs*8192 + i];
  float v = logf(s) - possim[i];

  __shared__ float sred[4];
  int t = threadIdx.x;
  #pragma unroll
  for (int o = 32; o; o >>= 1) v += __shfl_down(v, o);
  if ((t & 63) == 0) sred[t >> 6] = v;
  __syncthreads();
  if (t == 0) part[blockIdx.x] = sred[0]+sred[1]+sred[2]+sred[3];
}

// --------------------------- K4b: final combine -----------------------------
__global__ __launch_bounds__(256) void k_final(const float* __restrict__ part,
                                               const float* __restrict__ jsd_row,
                                               float* __restrict__ out){
  int t = threadIdx.x;
  float s = (t < 32) ? part[t] : 0.f;
  float j = 0.f;
  #pragma unroll
  for (int q = 0; q < 16; ++q) j += jsd_row[t + q*256];

  __shared__ float sr[4], jr[4];
  float ss = s, jj = j;
  #pragma unroll
  for (int o = 32; o; o >>= 1){ ss += __shfl_down(ss, o); jj += __shfl_down(jj, o); }
  if ((t & 63) == 0){ sr[t >> 6] = ss; jr[t >> 6] = jj; }
  __syncthreads();
  if (t == 0){
    float base = (sr[0]+sr[1]+sr[2]+sr[3]) / (8192.f * (1.f + 1e-5f));
    float jsd  = (jr[0]+jr[1]+jr[2]+jr[3]) / 4096.f;
    out[0] = base + jsd;   // LAM = 1
  }
}

// ---------------------------------------------------------------------------
extern "C" void kernel_launch(void* const* d_in, const int* in_sizes, int n_in,
                              void* d_out, int out_size, void* d_ws, size_t ws_size,
                              hipStream_t stream) {
  const float* mu     = (const float*)d_in[0];
  const float* mu_cap = (const float*)d_in[1];
  const float* lv     = (const float*)d_in[2];
  const float* lv_cap = (const float*)d_in[3];
  float* out = (float*)d_out;

  char* w = (char*)d_ws;
  unsigned short* Xn = (unsigned short*)w;                    // 8192*512*2 = 8 MB
  float* rowsumP = (float*)(w + 8388608);                     // NSLOT*8192*4 = 2 MB
  float* possim  = (float*)(w + 8388608 + 2097152);           // 32 KB
  float* jsd_row = (float*)(w + 8388608 + 2097152 + 32768);   // 16 KB
  float* part    = (float*)(w + 8388608 + 2097152 + 32768 + 16384); // 128 B

  k_feats  <<<NROWS, 256, 0, stream>>>(mu, mu_cap, lv, lv_cap, Xn);
  k_simlse <<<2080, 256, 0, stream>>>(Xn, rowsumP, possim);
  k_jsd    <<<BDIM, 256, 0, stream>>>(mu, mu_cap, lv, lv_cap, jsd_row);
  k_lsepart<<<32, 256, 0, stream>>>(rowsumP, possim, part);
  k_final  <<<1, 256, 0, stream>>>(part, jsd_row, out);
}

// Round 3
// 107.550 us; speedup vs baseline: 2.2182x; 1.1760x over previous
//
#include <hip/hip_runtime.h>
#include <hip/hip_bf16.h>
#include <stdint.h>

// ---------------------------------------------------------------------------
// DAReLoss: SupCon(reparam features) + JSD(normalized Gaussian stats)
// B=4096, D=512, N=2B=8192, TAU=1, LAM=1
// Round 3: 256^2 triangular sim/LSE GEMM with counted-vmcnt triple-buffer
// pipeline (T3+T4), pair-row XOR LDS swizzle (T2), setprio (T5), XCD swizzle
// (T1). k_jsd fused into k_feats.
// ---------------------------------------------------------------------------

typedef __attribute__((ext_vector_type(4))) float f32x4;
typedef __attribute__((ext_vector_type(8))) short bf16x8;

#define NROWS 8192
#define NSLOT 32

// ----------------------------- threefry-2x32 -------------------------------
__device__ __forceinline__ void tf_round(uint32_t& x0, uint32_t& x1, int r){
  x0 += x1;
  x1 = (x1 << r) | (x1 >> (32 - r));
  x1 ^= x0;
}

__device__ __forceinline__ void threefry2x32(uint32_t k0, uint32_t k1,
                                             uint32_t c0, uint32_t c1,
                                             uint32_t& o0, uint32_t& o1){
  uint32_t ks2 = k0 ^ k1 ^ 0x1BD11BDAu;
  uint32_t x0 = c0 + k0, x1 = c1 + k1;
  tf_round(x0,x1,13); tf_round(x0,x1,15); tf_round(x0,x1,26); tf_round(x0,x1,6);
  x0 += k1; x1 += ks2 + 1u;
  tf_round(x0,x1,17); tf_round(x0,x1,29); tf_round(x0,x1,16); tf_round(x0,x1,24);
  x0 += ks2; x1 += k0 + 2u;
  tf_round(x0,x1,13); tf_round(x0,x1,15); tf_round(x0,x1,26); tf_round(x0,x1,6);
  x0 += k0; x1 += k1 + 3u;
  tf_round(x0,x1,17); tf_round(x0,x1,29); tf_round(x0,x1,16); tf_round(x0,x1,24);
  x0 += k1; x1 += ks2 + 4u;
  tf_round(x0,x1,13); tf_round(x0,x1,15); tf_round(x0,x1,26); tf_round(x0,x1,6);
  x0 += ks2; x1 += k0 + 5u;
  o0 = x0; o1 = x1;
}

__device__ __forceinline__ float erfinv_f32(float x){
  float w = -log1pf(-x*x);
  float p;
  if (w < 5.0f){
    w -= 2.5f;
    p = 2.81022636e-08f;
    p = fmaf(p,w, 3.43273939e-07f);
    p = fmaf(p,w,-3.5233877e-06f);
    p = fmaf(p,w,-4.39150654e-06f);
    p = fmaf(p,w, 0.00021858087f);
    p = fmaf(p,w,-0.00125372503f);
    p = fmaf(p,w,-0.00417768164f);
    p = fmaf(p,w, 0.246640727f);
    p = fmaf(p,w, 1.50140941f);
  } else {
    w = sqrtf(w) - 3.0f;
    p = -0.000200214257f;
    p = fmaf(p,w, 0.000100950558f);
    p = fmaf(p,w, 0.00134934322f);
    p = fmaf(p,w,-0.00367342844f);
    p = fmaf(p,w, 0.00573950773f);
    p = fmaf(p,w,-0.0076224613f);
    p = fmaf(p,w, 0.00943887047f);
    p = fmaf(p,w, 1.00167406f);
    p = fmaf(p,w, 2.83297682f);
  }
  return p*x;
}

__device__ __forceinline__ float jax_normal_elem(uint32_t k0, uint32_t k1, uint32_t idx){
  uint32_t p = idx & 0xFFFFFu;
  uint32_t hi = idx >> 20;
  uint32_t o0, o1;
  threefry2x32(k0, k1, p, p + 0x100000u, o0, o1);
  uint32_t bits = hi ? o1 : o0;
  float f = __uint_as_float((bits >> 9) | 0x3F800000u) - 1.0f;
  const float lo = -0.99999994f;
  float v = fmaf(f, 2.0f, lo);
  v = fmaxf(lo, v);
  return 1.41421354f * erfinv_f32(v);
}

__device__ __forceinline__ unsigned short f2bf(float f){
  uint32_t u = __float_as_uint(f);
  u += 0x7FFFu + ((u >> 16) & 1u);   // RNE
  return (unsigned short)(u >> 16);
}

// ------------------- K1: features + normalize + JSD (fused) ----------------
// One block per batch row (4096). Reads mu/mu_cap/lv/lv_cap once; produces
// Xn rows r and r+4096 (bf16, L2-normalized reparam features) + jsd_row[r].
__global__ __launch_bounds__(256) void k_featsjsd(const float* __restrict__ mu,
                                                  const float* __restrict__ mu_cap,
                                                  const float* __restrict__ lv,
                                                  const float* __restrict__ lv_cap,
                                                  unsigned short* __restrict__ Xn,
                                                  float* __restrict__ jsd_row){
  int r = blockIdx.x;
  int t = threadIdx.x;
  size_t base = (size_t)r * 512;

  // split(key(42)): ek1=(a0,a1), ek2=(b0,b1)
  uint32_t a0,a1,b0,b1;
  threefry2x32(0u, 42u, 0u, 2u, a0, b0);
  threefry2x32(0u, 42u, 1u, 3u, a1, b1);

  float m[2], mc[2], av[2], bv[2], x[2], xc[2];
  float sx=0.f, sxc=0.f, sm=0.f, smc=0.f, sa=0.f, sb=0.f;
  #pragma unroll
  for (int q = 0; q < 2; ++q){
    int c = t + q*256;
    m[q]  = mu[base + c];     sm  += m[q]*m[q];
    mc[q] = mu_cap[base + c]; smc += mc[q]*mc[q];
    av[q] = lv[base + c];     sa  += av[q]*av[q];
    bv[q] = lv_cap[base + c]; sb  += bv[q]*bv[q];
    uint32_t idx = (uint32_t)r*512u + (uint32_t)c;
    float e1 = jax_normal_elem(a0, a1, idx);
    float e2 = jax_normal_elem(b0, b1, idx);
    x[q]  = m[q]  + expf(0.5f*av[q]) * e1;  sx  += x[q]*x[q];
    xc[q] = mc[q] + expf(0.5f*bv[q]) * e2;  sxc += xc[q]*xc[q];
  }

  __shared__ float sred[4][6];
  #pragma unroll
  for (int o = 32; o; o >>= 1){
    sx  += __shfl_down(sx,  o);  sxc += __shfl_down(sxc, o);
    sm  += __shfl_down(sm,  o);  smc += __shfl_down(smc, o);
    sa  += __shfl_down(sa,  o);  sb  += __shfl_down(sb,  o);
  }
  if ((t & 63) == 0){
    int w = t >> 6;
    sred[w][0]=sx; sred[w][1]=sxc; sred[w][2]=sm;
    sred[w][3]=smc; sred[w][4]=sa; sred[w][5]=sb;
  }
  __syncthreads();
  float tx  = sred[0][0]+sred[1][0]+sred[2][0]+sred[3][0];
  float txc = sred[0][1]+sred[1][1]+sred[2][1]+sred[3][1];
  float tm  = sred[0][2]+sred[1][2]+sred[2][2]+sred[3][2];
  float tmc = sred[0][3]+sred[1][3]+sred[2][3]+sred[3][3];
  float ta  = sred[0][4]+sred[1][4]+sred[2][4]+sred[3][4];
  float tb  = sred[0][5]+sred[1][5]+sred[2][5]+sred[3][5];
  float ix  = 1.f / fmaxf(sqrtf(tx),  1e-12f);
  float ixc = 1.f / fmaxf(sqrtf(txc), 1e-12f);
  float im  = 1.f / fmaxf(sqrtf(tm),  1e-12f);
  float imc = 1.f / fmaxf(sqrtf(tmc), 1e-12f);
  float ia  = 1.f / fmaxf(sqrtf(ta),  1e-12f);
  float ib  = 1.f / fmaxf(sqrtf(tb),  1e-12f);

  float accv = 0.f;
  #pragma unroll
  for (int q = 0; q < 2; ++q){
    int c = t + q*256;
    Xn[base + c]                       = f2bf(x[q]  * ix);
    Xn[(size_t)(4096 + r)*512 + c]     = f2bf(xc[q] * ixc);
    // JSD on normalized stats
    float an = m[q]*im, bn = mc[q]*imc;
    float al = av[q]*ia, bl = bv[q]*ib;
    float ea = expf(al), eb = expf(bl);
    float varm = 0.5f*(ea + eb);
    float lvm  = logf(varm + 1e-8f);
    float v2   = expf(lvm);
    float den  = v2 + 1e-8f;
    float dm   = 0.5f*(an - bn);
    float dm2  = dm*dm;
    float t1 = (ea + 1e-8f)/den + (lvm - al) + dm2/den - 1.f;
    float t2 = (eb + 1e-8f)/den + (lvm - bl) + dm2/den - 1.f;
    accv += t1 + t2;
  }
  __shared__ float sred2[4];
  #pragma unroll
  for (int o = 32; o; o >>= 1) accv += __shfl_down(accv, o);
  if ((t & 63) == 0) sred2[t >> 6] = accv;
  __syncthreads();
  if (t == 0)
    jsd_row[r] = 0.25f * (sred2[0]+sred2[1]+sred2[2]+sred2[3]);
}

// -------------------- K2: sim = Xn Xn^T (triangular), LSE ------------------
// 528 blocks = upper-triangle 256x256 tiles over 32 row-blocks. 512 threads
// = 8 waves (2M x 4N), per-wave 128x64, acc 8x4 frags. BK=32, 16 K-tiles.
// Triple-buffered LDS; stage tile kt+2 during kt (buffer (kt+2)%3 is free
// since kt-1's reads finished at kt's boundary barrier). Boundary wait is
// vmcnt(4) — counted, never a full drain until the last tile (T4).
// LDS pair-row XOR swizzle: byte = (row>>1)*128 + (((row&1)*4+c4)^((row>>1)&7))*16
// -> read idx8 = ((l15&1)*4+l4)^(l15>>1) is lane-constant; 64 lanes cover all
// 8 bank-groups exactly twice per 128B region (2-way = free, m136). Write side
// keeps global_load_lds dest linear; the GLOBAL source is pre-swizzled (m173).
__device__ __forceinline__ void gload_lds16(const unsigned short* g, unsigned short* l){
  __builtin_amdgcn_global_load_lds(
      (const __attribute__((address_space(1))) void*)g,
      (__attribute__((address_space(3))) void*)l, 16, 0, 0);
}

__global__ __launch_bounds__(512, 2) void k_simlse(const unsigned short* __restrict__ Xn,
                                                   float* __restrict__ rowsumP, // [NSLOT][8192]
                                                   float* __restrict__ possim){ // [8192]
  // XCD-chunked bijective swizzle: 528 = 8*66
  int bid = (blockIdx.x & 7)*66 + (blockIdx.x >> 3);
  int tt = bid, rb = 0, rem = 32;
  while (tt >= rem){ tt -= rem; --rem; ++rb; }
  int cb = rb + tt;
  int rowbase = rb*256, colbase = cb*256;
  bool diag    = (rb == cb);
  bool postile = (cb == rb + 16);

  __shared__ unsigned short SA[3*8192];   // 3 x [256][32] bf16, swizzled
  __shared__ unsigned short SB[3*8192];
  __shared__ float redR[4][256];
  __shared__ float redC[2][256];

  int tid = threadIdx.x;
  int wid = tid >> 6, l = tid & 63;
  int wr = wid >> 2, wn = wid & 3;     // 2 x 4 wave grid
  int l15 = l & 15, l4 = l >> 4;

  // staging source pre-swizzle (per-lane constants)
  int prow = (l >> 3)*2 + (((l & 7) ^ (l >> 3)) >> 2);
  int pcol = (((l & 7) ^ (l >> 3)) & 3) * 8;

  // ds_read frag addressing (ushort units)
  const int idx8 = (((l15 & 1) << 2) | l4) ^ (l15 >> 1);
  const int aoff = wr*4096 + (l15 >> 1)*64 + idx8*8;  // + mh*2048 + mi*512
  const int boff = wn*2048 + (l15 >> 1)*64 + idx8*8;  // + n*512

  f32x4 acc[8][4];
  #pragma unroll
  for (int m = 0; m < 8; ++m)
    #pragma unroll
    for (int n = 0; n < 4; ++n) acc[m][n] = f32x4{0.f,0.f,0.f,0.f};

  // ---- prologue: stage tiles 0 and 1 ----
  #pragma unroll
  for (int t0 = 0; t0 < 2; ++t0){
    const unsigned short* ga = Xn + (size_t)(rowbase + wid*32 + prow)*512 + t0*32 + pcol;
    const unsigned short* gb = Xn + (size_t)(colbase + wid*32 + prow)*512 + t0*32 + pcol;
    gload_lds16(ga,          &SA[t0*8192 + (wid*2  )*512]);
    gload_lds16(ga + 16*512, &SA[t0*8192 + (wid*2+1)*512]);
    gload_lds16(gb,          &SB[t0*8192 + (wid*2  )*512]);
    gload_lds16(gb + 16*512, &SB[t0*8192 + (wid*2+1)*512]);
  }

  // ---- main loop: 16 K-tiles of 32 ----
  for (int kt = 0; kt < 16; ++kt){
    int tbuf = kt % 3;
    int sbuf = (kt + 2) % 3;

    if (kt < 15) asm volatile("s_waitcnt vmcnt(4)" ::: "memory");
    else         asm volatile("s_waitcnt vmcnt(0)" ::: "memory");
    __builtin_amdgcn_s_barrier();
    __builtin_amdgcn_sched_barrier(0);

    const unsigned short* SAb = &SA[tbuf*8192];
    const unsigned short* SBb = &SB[tbuf*8192];

    // ---- phase 0: stage A(kt+2), read B + A-half0, 16 MFMA ----
    if (kt + 2 < 16){
      const unsigned short* g0 = Xn + (size_t)(rowbase + wid*32 + prow)*512 + (kt+2)*32 + pcol;
      gload_lds16(g0,          &SA[sbuf*8192 + (wid*2  )*512]);
      gload_lds16(g0 + 16*512, &SA[sbuf*8192 + (wid*2+1)*512]);
    }
    bf16x8 bfr[4];
    #pragma unroll
    for (int n = 0; n < 4; ++n)
      bfr[n] = *(const bf16x8*)&SBb[boff + n*512];
    {
      bf16x8 af[4];
      #pragma unroll
      for (int mi = 0; mi < 4; ++mi)
        af[mi] = *(const bf16x8*)&SAb[aoff + mi*512];
      __builtin_amdgcn_s_setprio(1);
      #pragma unroll
      for (int mi = 0; mi < 4; ++mi)
        #pragma unroll
        for (int n = 0; n < 4; ++n)
          acc[mi][n] = __builtin_amdgcn_mfma_f32_16x16x32_bf16(af[mi], bfr[n], acc[mi][n], 0, 0, 0);
      __builtin_amdgcn_s_setprio(0);
    }
    __builtin_amdgcn_sched_barrier(0);

    // ---- phase 1: stage B(kt+2), read A-half1, 16 MFMA ----
    if (kt + 2 < 16){
      const unsigned short* g0 = Xn + (size_t)(colbase + wid*32 + prow)*512 + (kt+2)*32 + pcol;
      gload_lds16(g0,          &SB[sbuf*8192 + (wid*2  )*512]);
      gload_lds16(g0 + 16*512, &SB[sbuf*8192 + (wid*2+1)*512]);
    }
    {
      bf16x8 af[4];
      #pragma unroll
      for (int mi = 0; mi < 4; ++mi)
        af[mi] = *(const bf16x8*)&SAb[aoff + 2048 + mi*512];
      __builtin_amdgcn_s_setprio(1);
      #pragma unroll
      for (int mi = 0; mi < 4; ++mi)
        #pragma unroll
        for (int n = 0; n < 4; ++n)
          acc[4+mi][n] = __builtin_amdgcn_mfma_f32_16x16x32_bf16(af[mi], bfr[n], acc[4+mi][n], 0, 0, 0);
      __builtin_amdgcn_s_setprio(0);
    }
    __builtin_amdgcn_sched_barrier(0);
  }

  // ---- epilogue: pos-pair grab, masks, exp in-place ----
  #pragma unroll
  for (int m = 0; m < 8; ++m){
    #pragma unroll
    for (int n = 0; n < 4; ++n){
      int col_l = wn*64 + n*16 + l15;
      #pragma unroll
      for (int r = 0; r < 4; ++r){
        int row_l = wr*128 + m*16 + l4*4 + r;
        float v = acc[m][n][r];
        if (postile && row_l == col_l){
          possim[rowbase + row_l] = v;    // row i, pos col i+4096
          possim[colbase + col_l] = v;    // row i+4096, pos col i (sym)
        }
        float e = __expf(v);
        if (diag && row_l == col_l) e = 0.f;
        acc[m][n][r] = e;
      }
    }
  }

  // row-sums (slot cb): reduce across 16 col-lanes
  #pragma unroll
  for (int m = 0; m < 8; ++m){
    #pragma unroll
    for (int r = 0; r < 4; ++r){
      float s = acc[m][0][r] + acc[m][1][r] + acc[m][2][r] + acc[m][3][r];
      s += __shfl_xor(s, 1); s += __shfl_xor(s, 2);
      s += __shfl_xor(s, 4); s += __shfl_xor(s, 8);
      if (l15 == 0) redR[wn][wr*128 + m*16 + l4*4 + r] = s;
    }
  }
  // col-sums (slot rb): reduce across l4 groups
  #pragma unroll
  for (int n = 0; n < 4; ++n){
    float s = 0.f;
    #pragma unroll
    for (int m = 0; m < 8; ++m)
      #pragma unroll
      for (int r = 0; r < 4; ++r) s += acc[m][n][r];
    s += __shfl_xor(s, 16); s += __shfl_xor(s, 32);
    if (l4 == 0) redC[wr][wn*64 + n*16 + l15] = s;
  }
  __syncthreads();
  if (tid < 256){
    float rs = redR[0][tid] + redR[1][tid] + redR[2][tid] + redR[3][tid];
    rowsumP[(size_t)cb*8192 + rowbase + tid] = rs;
    if (!diag){
      float cs = redC[0][tid] + redC[1][tid];
      rowsumP[(size_t)rb*8192 + colbase + tid] = cs;
    }
  }
}

// ------------------- K3a: per-256-row (lse - pos) partials ------------------
__global__ __launch_bounds__(256) void k_lsepart(const float* __restrict__ rowsumP,
                                                 const float* __restrict__ possim,
                                                 float* __restrict__ part){
  int i = blockIdx.x*256 + threadIdx.x;
  float s = 0.f;
  #pragma unroll 8
  for (int cs = 0; cs < NSLOT; ++cs) s += rowsumP[(size_t)cs*8192 + i];
  float v = logf(s) - possim[i];

  __shared__ float sred[4];
  int t = threadIdx.x;
  #pragma unroll
  for (int o = 32; o; o >>= 1) v += __shfl_down(v, o);
  if ((t & 63) == 0) sred[t >> 6] = v;
  __syncthreads();
  if (t == 0) part[blockIdx.x] = sred[0]+sred[1]+sred[2]+sred[3];
}

// --------------------------- K3b: final combine -----------------------------
__global__ __launch_bounds__(256) void k_final(const float* __restrict__ part,
                                               const float* __restrict__ jsd_row,
                                               float* __restrict__ out){
  int t = threadIdx.x;
  float s = (t < 32) ? part[t] : 0.f;
  float j = 0.f;
  #pragma unroll
  for (int q = 0; q < 16; ++q) j += jsd_row[t + q*256];

  __shared__ float sr[4], jr[4];
  float ss = s, jj = j;
  #pragma unroll
  for (int o = 32; o; o >>= 1){ ss += __shfl_down(ss, o); jj += __shfl_down(jj, o); }
  if ((t & 63) == 0){ sr[t >> 6] = ss; jr[t >> 6] = jj; }
  __syncthreads();
  if (t == 0){
    float base = (sr[0]+sr[1]+sr[2]+sr[3]) / (8192.f * (1.f + 1e-5f));
    float jsd  = (jr[0]+jr[1]+jr[2]+jr[3]) / 4096.f;
    out[0] = base + jsd;   // LAM = 1
  }
}

// ---------------------------------------------------------------------------
extern "C" void kernel_launch(void* const* d_in, const int* in_sizes, int n_in,
                              void* d_out, int out_size, void* d_ws, size_t ws_size,
                              hipStream_t stream) {
  const float* mu     = (const float*)d_in[0];
  const float* mu_cap = (const float*)d_in[1];
  const float* lv     = (const float*)d_in[2];
  const float* lv_cap = (const float*)d_in[3];
  float* out = (float*)d_out;

  char* w = (char*)d_ws;
  unsigned short* Xn = (unsigned short*)w;                    // 8192*512*2 = 8 MB
  float* rowsumP = (float*)(w + 8388608);                     // 32*8192*4 = 1 MB
  float* possim  = (float*)(w + 8388608 + 1048576);           // 32 KB
  float* jsd_row = (float*)(w + 8388608 + 1048576 + 32768);   // 16 KB
  float* part    = (float*)(w + 8388608 + 1048576 + 32768 + 16384); // 128 B

  k_featsjsd<<<4096, 256, 0, stream>>>(mu, mu_cap, lv, lv_cap, Xn, jsd_row);
  k_simlse  <<<528,  512, 0, stream>>>(Xn, rowsumP, possim);
  k_lsepart <<<32,   256, 0, stream>>>(rowsumP, possim, part);
  k_final   <<<1,    256, 0, stream>>>(part, jsd_row, out);
}

// Round 4
// 102.245 us; speedup vs baseline: 2.3332x; 1.0519x over previous
//
#include <hip/hip_runtime.h>
#include <hip/hip_bf16.h>
#include <stdint.h>

// ---------------------------------------------------------------------------
// DAReLoss: SupCon(reparam features) + JSD(normalized Gaussian stats)
// B=4096, D=512, N=2B=8192, TAU=1, LAM=1
// Round 4: 8-phase-style schedule on the 256^2 triangular sim/LSE GEMM:
//   ring of 4 LDS slots per operand (256x32 bf16, swizzled), phase=(gk,mh):
//   {ds_read, stage 1 half-tile, barrier, lgkm(0), setprio, 16 MFMA, barrier},
//   counted vmcnt(8/4/0) ledger. Packing fix: grid=512 = 496 off-diag blocks
//   + 16 dual-diagonal blocks (dispatched early) -> ~2T makespan.
// ---------------------------------------------------------------------------

typedef __attribute__((ext_vector_type(4))) float f32x4;
typedef __attribute__((ext_vector_type(8))) short bf16x8;

#define NROWS 8192
#define NSLOT 32
#define NGK   16        // K / 32

// ----------------------------- threefry-2x32 -------------------------------
__device__ __forceinline__ void tf_round(uint32_t& x0, uint32_t& x1, int r){
  x0 += x1;
  x1 = (x1 << r) | (x1 >> (32 - r));
  x1 ^= x0;
}

__device__ __forceinline__ void threefry2x32(uint32_t k0, uint32_t k1,
                                             uint32_t c0, uint32_t c1,
                                             uint32_t& o0, uint32_t& o1){
  uint32_t ks2 = k0 ^ k1 ^ 0x1BD11BDAu;
  uint32_t x0 = c0 + k0, x1 = c1 + k1;
  tf_round(x0,x1,13); tf_round(x0,x1,15); tf_round(x0,x1,26); tf_round(x0,x1,6);
  x0 += k1; x1 += ks2 + 1u;
  tf_round(x0,x1,17); tf_round(x0,x1,29); tf_round(x0,x1,16); tf_round(x0,x1,24);
  x0 += ks2; x1 += k0 + 2u;
  tf_round(x0,x1,13); tf_round(x0,x1,15); tf_round(x0,x1,26); tf_round(x0,x1,6);
  x0 += k0; x1 += k1 + 3u;
  tf_round(x0,x1,17); tf_round(x0,x1,29); tf_round(x0,x1,16); tf_round(x0,x1,24);
  x0 += k1; x1 += ks2 + 4u;
  tf_round(x0,x1,13); tf_round(x0,x1,15); tf_round(x0,x1,26); tf_round(x0,x1,6);
  x0 += ks2; x1 += k0 + 5u;
  o0 = x0; o1 = x1;
}

__device__ __forceinline__ float erfinv_f32(float x){
  float w = -log1pf(-x*x);
  float p;
  if (w < 5.0f){
    w -= 2.5f;
    p = 2.81022636e-08f;
    p = fmaf(p,w, 3.43273939e-07f);
    p = fmaf(p,w,-3.5233877e-06f);
    p = fmaf(p,w,-4.39150654e-06f);
    p = fmaf(p,w, 0.00021858087f);
    p = fmaf(p,w,-0.00125372503f);
    p = fmaf(p,w,-0.00417768164f);
    p = fmaf(p,w, 0.246640727f);
    p = fmaf(p,w, 1.50140941f);
  } else {
    w = sqrtf(w) - 3.0f;
    p = -0.000200214257f;
    p = fmaf(p,w, 0.000100950558f);
    p = fmaf(p,w, 0.00134934322f);
    p = fmaf(p,w,-0.00367342844f);
    p = fmaf(p,w, 0.00573950773f);
    p = fmaf(p,w,-0.0076224613f);
    p = fmaf(p,w, 0.00943887047f);
    p = fmaf(p,w, 1.00167406f);
    p = fmaf(p,w, 2.83297682f);
  }
  return p*x;
}

__device__ __forceinline__ float jax_normal_elem(uint32_t k0, uint32_t k1, uint32_t idx){
  uint32_t p = idx & 0xFFFFFu;
  uint32_t hi = idx >> 20;
  uint32_t o0, o1;
  threefry2x32(k0, k1, p, p + 0x100000u, o0, o1);
  uint32_t bits = hi ? o1 : o0;
  float f = __uint_as_float((bits >> 9) | 0x3F800000u) - 1.0f;
  const float lo = -0.99999994f;
  float v = fmaf(f, 2.0f, lo);
  v = fmaxf(lo, v);
  return 1.41421354f * erfinv_f32(v);
}

__device__ __forceinline__ unsigned short f2bf(float f){
  uint32_t u = __float_as_uint(f);
  u += 0x7FFFu + ((u >> 16) & 1u);   // RNE
  return (unsigned short)(u >> 16);
}

// ------------------- K1: features + normalize + JSD (fused) ----------------
__global__ __launch_bounds__(256) void k_featsjsd(const float* __restrict__ mu,
                                                  const float* __restrict__ mu_cap,
                                                  const float* __restrict__ lv,
                                                  const float* __restrict__ lv_cap,
                                                  unsigned short* __restrict__ Xn,
                                                  float* __restrict__ jsd_row){
  int r = blockIdx.x;
  int t = threadIdx.x;
  size_t base = (size_t)r * 512;

  uint32_t a0,a1,b0,b1;
  threefry2x32(0u, 42u, 0u, 2u, a0, b0);
  threefry2x32(0u, 42u, 1u, 3u, a1, b1);

  float2 m2  = *(const float2*)(mu     + base + 2*t);
  float2 mc2 = *(const float2*)(mu_cap + base + 2*t);
  float2 av2 = *(const float2*)(lv     + base + 2*t);
  float2 bv2 = *(const float2*)(lv_cap + base + 2*t);
  float m[2]  = {m2.x,  m2.y};
  float mc[2] = {mc2.x, mc2.y};
  float av[2] = {av2.x, av2.y};
  float bv[2] = {bv2.x, bv2.y};

  float x[2], xc[2];
  float sx=0.f, sxc=0.f, sm=0.f, smc=0.f, sa=0.f, sb=0.f;
  #pragma unroll
  for (int q = 0; q < 2; ++q){
    sm  += m[q]*m[q];   smc += mc[q]*mc[q];
    sa  += av[q]*av[q]; sb  += bv[q]*bv[q];
    uint32_t idx = (uint32_t)r*512u + (uint32_t)(2*t + q);
    float e1 = jax_normal_elem(a0, a1, idx);
    float e2 = jax_normal_elem(b0, b1, idx);
    x[q]  = m[q]  + __expf(0.5f*av[q]) * e1;  sx  += x[q]*x[q];
    xc[q] = mc[q] + __expf(0.5f*bv[q]) * e2;  sxc += xc[q]*xc[q];
  }

  __shared__ float sred[4][6];
  #pragma unroll
  for (int o = 32; o; o >>= 1){
    sx  += __shfl_down(sx,  o);  sxc += __shfl_down(sxc, o);
    sm  += __shfl_down(sm,  o);  smc += __shfl_down(smc, o);
    sa  += __shfl_down(sa,  o);  sb  += __shfl_down(sb,  o);
  }
  if ((t & 63) == 0){
    int w = t >> 6;
    sred[w][0]=sx; sred[w][1]=sxc; sred[w][2]=sm;
    sred[w][3]=smc; sred[w][4]=sa; sred[w][5]=sb;
  }
  __syncthreads();
  float tx  = sred[0][0]+sred[1][0]+sred[2][0]+sred[3][0];
  float txc = sred[0][1]+sred[1][1]+sred[2][1]+sred[3][1];
  float tm  = sred[0][2]+sred[1][2]+sred[2][2]+sred[3][2];
  float tmc = sred[0][3]+sred[1][3]+sred[2][3]+sred[3][3];
  float ta  = sred[0][4]+sred[1][4]+sred[2][4]+sred[3][4];
  float tb  = sred[0][5]+sred[1][5]+sred[2][5]+sred[3][5];
  float ix  = 1.f / fmaxf(sqrtf(tx),  1e-12f);
  float ixc = 1.f / fmaxf(sqrtf(txc), 1e-12f);
  float im  = 1.f / fmaxf(sqrtf(tm),  1e-12f);
  float imc = 1.f / fmaxf(sqrtf(tmc), 1e-12f);
  float ia  = 1.f / fmaxf(sqrtf(ta),  1e-12f);
  float ib  = 1.f / fmaxf(sqrtf(tb),  1e-12f);

  unsigned short xb[2], xcb[2];
  float accv = 0.f;
  #pragma unroll
  for (int q = 0; q < 2; ++q){
    xb[q]  = f2bf(x[q]  * ix);
    xcb[q] = f2bf(xc[q] * ixc);
    float an = m[q]*im, bn = mc[q]*imc;
    float al = av[q]*ia, bl = bv[q]*ib;
    float ea = __expf(al), eb = __expf(bl);
    float varm = 0.5f*(ea + eb);
    float lvm  = __logf(varm + 1e-8f);
    float v2   = __expf(lvm);
    float den  = v2 + 1e-8f;
    float dm   = 0.5f*(an - bn);
    float dm2  = dm*dm;
    float t1 = (ea + 1e-8f)/den + (lvm - al) + dm2/den - 1.f;
    float t2 = (eb + 1e-8f)/den + (lvm - bl) + dm2/den - 1.f;
    accv += t1 + t2;
  }
  *(uint32_t*)&Xn[base + 2*t]                   = *(uint32_t*)xb;
  *(uint32_t*)&Xn[(size_t)(4096 + r)*512 + 2*t] = *(uint32_t*)xcb;

  __shared__ float sred2[4];
  #pragma unroll
  for (int o = 32; o; o >>= 1) accv += __shfl_down(accv, o);
  if ((t & 63) == 0) sred2[t >> 6] = accv;
  __syncthreads();
  if (t == 0)
    jsd_row[r] = 0.25f * (sred2[0]+sred2[1]+sred2[2]+sred2[3]);
}

// -------------------- K2: sim = Xn Xn^T (triangular), LSE ------------------
// Swizzle (verified round 3, PMC conflicts = 0): slot layout [256][32] bf16,
// read idx8 = ((l15&1)*4+l4)^(l15>>1); global src pre-swizzled (prow/pcol)
// so global_load_lds keeps a linear destination.
__device__ __forceinline__ void gload_lds16(const unsigned short* g, unsigned short* l){
  __builtin_amdgcn_global_load_lds(
      (const __attribute__((address_space(1))) void*)g,
      (__attribute__((address_space(3))) void*)l, 16, 0, 0);
}

__device__ __forceinline__ void stage_slot(const unsigned short* __restrict__ Xn,
                                           unsigned short* S, int slot, int pbase,
                                           int gk, int wid, int prow, int pcol){
  const unsigned short* g = Xn + (size_t)(pbase + wid*32 + prow)*512 + gk*32 + pcol;
  gload_lds16(g,          &S[slot*8192 + (wid*2  )*512]);
  gload_lds16(g + 16*512, &S[slot*8192 + (wid*2+1)*512]);
}

__global__ __launch_bounds__(512, 1) void k_simlse(const unsigned short* __restrict__ Xn,
                                                   float* __restrict__ rowsumP, // [NSLOT][8192]
                                                   float* __restrict__ possim){ // [8192]
  // XCD-chunked bijective swizzle (512 = 8*64); dual-diag blocks are raw%8==0
  int bid = (blockIdx.x & 7)*64 + (blockIdx.x >> 3);

  __shared__ unsigned short SA[4*8192];   // ring: 4 slots x [256][32] bf16
  __shared__ unsigned short SB[4*8192];
  __shared__ float redR[4][256];
  __shared__ float redC[2][256];

  int tid = threadIdx.x;
  int wid = tid >> 6, l = tid & 63;
  int wr = wid >> 2, wn = wid & 3;     // 2 x 4 wave grid
  int l15 = l & 15, l4 = l >> 4;

  // staging source pre-swizzle (per-lane constants)
  int prow = (l >> 3)*2 + (((l & 7) ^ (l >> 3)) >> 2);
  int pcol = (((l & 7) ^ (l >> 3)) & 3) * 8;

  // ds_read frag addressing (ushort units)
  const int idx8 = (((l15 & 1) << 2) | l4) ^ (l15 >> 1);
  const int aoff = wr*4096 + (l15 >> 1)*64 + idx8*8;  // + mh*2048 + mi*512
  const int boff = wn*2048 + (l15 >> 1)*64 + idx8*8;  // + n*512

  // tile list: bid<16 -> two diagonal tiles; else one off-diagonal tile
  int ntile, rb0, cb0, rb1, cb1;
  if (bid < 16){
    ntile = 2;
    rb0 = cb0 = 2*bid;
    rb1 = cb1 = 2*bid + 1;
  } else {
    ntile = 1;
    int j = bid - 16, rbb = 0, rem = 31;
    while (j >= rem){ j -= rem; --rem; ++rbb; }
    rb0 = rbb; cb0 = rbb + 1 + j;
    rb1 = cb1 = 0;
  }

  for (int tile = 0; tile < ntile; ++tile){
    int rb = tile ? rb1 : rb0;
    int cb = tile ? cb1 : cb0;
    int rowbase = rb*256, colbase = cb*256;
    bool diag    = (rb == cb);
    bool postile = (cb == rb + 16);

    f32x4 acc[8][4];
    #pragma unroll
    for (int m = 0; m < 8; ++m)
      #pragma unroll
      for (int n = 0; n < 4; ++n) acc[m][n] = f32x4{0.f,0.f,0.f,0.f};

    if (tile) __syncthreads();   // protect SA/SB + redR/redC reuse

    // ---- prologue: stage gk = 0,1,2 (A,B interleaved: ledger order) ----
    #pragma unroll
    for (int g0 = 0; g0 < 3; ++g0){
      stage_slot(Xn, SA, g0, rowbase, g0, wid, prow, pcol);
      stage_slot(Xn, SB, g0, colbase, g0, wid, prow, pcol);
      __builtin_amdgcn_sched_barrier(0);
    }

    // ---- main loop: 16 gk x 2 phases (mh0, mh1) ----
    for (int gk = 0; gk < NGK; ++gk){
      const unsigned short* SAb = &SA[(gk & 3)*8192];
      const unsigned short* SBb = &SB[(gk & 3)*8192];
      int sgk = gk + 3;
      int ss  = sgk & 3;

      // vmcnt ledger: stages after {A(gk),B(gk)} = pairs gk+1,gk+2 (2 gloads
      // per stage): gk<=13 -> 8 outstanding allowed; gk==14 -> 4; gk==15 -> 0.
      if (gk <= NGK-3)      asm volatile("s_waitcnt vmcnt(8)" ::: "memory");
      else if (gk == NGK-2) asm volatile("s_waitcnt vmcnt(4)" ::: "memory");
      else                  asm volatile("s_waitcnt vmcnt(0)" ::: "memory");
      __builtin_amdgcn_s_barrier();

      // ---------- phase (gk, mh0): read B + A-half0, stage A(gk+3) --------
      bf16x8 bfr[4], af[4];
      #pragma unroll
      for (int n = 0; n < 4; ++n)
        bfr[n] = *(const bf16x8*)&SBb[boff + n*512];
      #pragma unroll
      for (int mi = 0; mi < 4; ++mi)
        af[mi] = *(const bf16x8*)&SAb[aoff + mi*512];
      if (sgk < NGK) stage_slot(Xn, SA, ss, rowbase, sgk, wid, prow, pcol);
      asm volatile("s_waitcnt lgkmcnt(0)" ::: "memory");
      __builtin_amdgcn_sched_barrier(0);
      __builtin_amdgcn_s_setprio(1);
      #pragma unroll
      for (int mi = 0; mi < 4; ++mi)
        #pragma unroll
        for (int n = 0; n < 4; ++n)
          acc[mi][n] = __builtin_amdgcn_mfma_f32_16x16x32_bf16(af[mi], bfr[n], acc[mi][n], 0, 0, 0);
      __builtin_amdgcn_s_setprio(0);
      __builtin_amdgcn_s_barrier();

      // ---------- phase (gk, mh1): read A-half1, stage B(gk+3) ------------
      #pragma unroll
      for (int mi = 0; mi < 4; ++mi)
        af[mi] = *(const bf16x8*)&SAb[aoff + 2048 + mi*512];
      if (sgk < NGK) stage_slot(Xn, SB, ss, colbase, sgk, wid, prow, pcol);
      asm volatile("s_waitcnt lgkmcnt(0)" ::: "memory");
      __builtin_amdgcn_sched_barrier(0);
      __builtin_amdgcn_s_setprio(1);
      #pragma unroll
      for (int mi = 0; mi < 4; ++mi)
        #pragma unroll
        for (int n = 0; n < 4; ++n)
          acc[4+mi][n] = __builtin_amdgcn_mfma_f32_16x16x32_bf16(af[mi], bfr[n], acc[4+mi][n], 0, 0, 0);
      __builtin_amdgcn_s_setprio(0);
      __builtin_amdgcn_s_barrier();
    }

    // ---- epilogue: pos-pair grab, masks, exp, partial sums ----
    #pragma unroll
    for (int m = 0; m < 8; ++m){
      #pragma unroll
      for (int n = 0; n < 4; ++n){
        int col_l = wn*64 + n*16 + l15;
        #pragma unroll
        for (int r = 0; r < 4; ++r){
          int row_l = wr*128 + m*16 + l4*4 + r;
          float v = acc[m][n][r];
          if (postile && row_l == col_l){
            possim[rowbase + row_l] = v;    // row i, pos col i+4096
            possim[colbase + col_l] = v;    // row i+4096, pos col i (sym)
          }
          float e = __expf(v);
          if (diag && row_l == col_l) e = 0.f;
          acc[m][n][r] = e;
        }
      }
    }

    // row-sums (slot cb): reduce across 16 col-lanes
    #pragma unroll
    for (int m = 0; m < 8; ++m){
      #pragma unroll
      for (int r = 0; r < 4; ++r){
        float s = acc[m][0][r] + acc[m][1][r] + acc[m][2][r] + acc[m][3][r];
        s += __shfl_xor(s, 1); s += __shfl_xor(s, 2);
        s += __shfl_xor(s, 4); s += __shfl_xor(s, 8);
        if (l15 == 0) redR[wn][wr*128 + m*16 + l4*4 + r] = s;
      }
    }
    // col-sums (slot rb): reduce across l4 groups
    #pragma unroll
    for (int n = 0; n < 4; ++n){
      float s = 0.f;
      #pragma unroll
      for (int m = 0; m < 8; ++m)
        #pragma unroll
        for (int r = 0; r < 4; ++r) s += acc[m][n][r];
      s += __shfl_xor(s, 16); s += __shfl_xor(s, 32);
      if (l4 == 0) redC[wr][wn*64 + n*16 + l15] = s;
    }
    __syncthreads();
    if (tid < 256){
      float rs = redR[0][tid] + redR[1][tid] + redR[2][tid] + redR[3][tid];
      rowsumP[(size_t)cb*8192 + rowbase + tid] = rs;
      if (!diag){
        float cs = redC[0][tid] + redC[1][tid];
        rowsumP[(size_t)rb*8192 + colbase + tid] = cs;
      }
    }
  }
}

// ------------------- K3a: per-256-row (lse - pos) partials ------------------
__global__ __launch_bounds__(256) void k_lsepart(const float* __restrict__ rowsumP,
                                                 const float* __restrict__ possim,
                                                 float* __restrict__ part){
  int i = blockIdx.x*256 + threadIdx.x;
  float s = 0.f;
  #pragma unroll 8
  for (int cs = 0; cs < NSLOT; ++cs) s += rowsumP[(size_t)cs*8192 + i];
  float v = __logf(s) - possim[i];

  __shared__ float sred[4];
  int t = threadIdx.x;
  #pragma unroll
  for (int o = 32; o; o >>= 1) v += __shfl_down(v, o);
  if ((t & 63) == 0) sred[t >> 6] = v;
  __syncthreads();
  if (t == 0) part[blockIdx.x] = sred[0]+sred[1]+sred[2]+sred[3];
}

// --------------------------- K3b: final combine -----------------------------
__global__ __launch_bounds__(256) void k_final(const float* __restrict__ part,
                                               const float* __restrict__ jsd_row,
                                               float* __restrict__ out){
  int t = threadIdx.x;
  float s = (t < 32) ? part[t] : 0.f;
  float j = 0.f;
  #pragma unroll
  for (int q = 0; q < 16; ++q) j += jsd_row[t + q*256];

  __shared__ float sr[4], jr[4];
  float ss = s, jj = j;
  #pragma unroll
  for (int o = 32; o; o >>= 1){ ss += __shfl_down(ss, o); jj += __shfl_down(jj, o); }
  if ((t & 63) == 0){ sr[t >> 6] = ss; jr[t >> 6] = jj; }
  __syncthreads();
  if (t == 0){
    float base = (sr[0]+sr[1]+sr[2]+sr[3]) / (8192.f * (1.f + 1e-5f));
    float jsd  = (jr[0]+jr[1]+jr[2]+jr[3]) / 4096.f;
    out[0] = base + jsd;   // LAM = 1
  }
}

// ---------------------------------------------------------------------------
extern "C" void kernel_launch(void* const* d_in, const int* in_sizes, int n_in,
                              void* d_out, int out_size, void* d_ws, size_t ws_size,
                              hipStream_t stream) {
  const float* mu     = (const float*)d_in[0];
  const float* mu_cap = (const float*)d_in[1];
  const float* lv     = (const float*)d_in[2];
  const float* lv_cap = (const float*)d_in[3];
  float* out = (float*)d_out;

  char* w = (char*)d_ws;
  unsigned short* Xn = (unsigned short*)w;                    // 8192*512*2 = 8 MB
  float* rowsumP = (float*)(w + 8388608);                     // 32*8192*4 = 1 MB
  float* possim  = (float*)(w + 8388608 + 1048576);           // 32 KB
  float* jsd_row = (float*)(w + 8388608 + 1048576 + 32768);   // 16 KB
  float* part    = (float*)(w + 8388608 + 1048576 + 32768 + 16384); // 128 B

  k_featsjsd<<<4096, 256, 0, stream>>>(mu, mu_cap, lv, lv_cap, Xn, jsd_row);
  k_simlse  <<<512,  512, 0, stream>>>(Xn, rowsumP, possim);
  k_lsepart <<<32,   256, 0, stream>>>(rowsumP, possim, part);
  k_final   <<<1,    256, 0, stream>>>(part, jsd_row, out);
}